// Round 18
// baseline (1575.086 us; speedup 1.0000x reference)
//
#include <hip/hip_runtime.h>

typedef unsigned short bf16;
typedef __attribute__((ext_vector_type(8))) short bf16x8;
typedef __attribute__((ext_vector_type(4))) float f32x4;
typedef unsigned short u16x4 __attribute__((ext_vector_type(4)));

#define DEVFN static __device__ __forceinline__

#define NL 12

#define VMW(N) asm volatile("s_waitcnt vmcnt(" #N ")" ::: "memory")
#define RBAR() asm volatile("s_barrier" ::: "memory")
#define SCHB() __builtin_amdgcn_sched_barrier(0)

DEVFN unsigned short f2bf(float f) {
  union { float f; unsigned u; } v; v.f = f;
  unsigned u = v.u;
  unsigned r = (u + 0x7fffu + ((u >> 16) & 1u)) >> 16;  // RNE
  return (unsigned short)r;
}
DEVFN float bf2f(unsigned short h) {
  union { unsigned u; float f; } v; v.u = ((unsigned)h) << 16; return v.f;
}
// truncation hi/lo split: 4 ALU ops, pair error ~2^-18
DEVFN void tsplit(float v, unsigned short& h, unsigned short& l) {
  union { float f; unsigned u; } a; a.f = v;
  h = (unsigned short)(a.u >> 16);
  union { float f; unsigned u; } b; b.u = a.u & 0xffff0000u;
  union { float f; unsigned u; } c; c.f = v - b.f;
  l = (unsigned short)(c.u >> 16);
}
// async global->LDS, 16B per lane; dest = wave-uniform base + lane*16
DEVFN void gll16(const bf16* g, bf16* l) {
  __builtin_amdgcn_global_load_lds(
      (const __attribute__((address_space(1))) unsigned int*)g,
      (__attribute__((address_space(3))) unsigned int*)l, 16, 0, 0);
}

#define MFMA_BF16(a, b, c) __builtin_amdgcn_mfma_f32_16x16x32_bf16((a), (b), (c), 0, 0, 0)

// ---------------------------------------------------------------------------
// Weight prep v2: one thread per WEIGHT ELEMENT (hi+lo computed together).
// Wq/bq folded with Cs = log2(e)/8. Per-layer bf16 block (1310720):
//   [0,196608) Wqkv hi | [196608,393216) Wqkv lo | [393216,524288) unused
//   [524288,786432) W1eff hi | [786432,1048576) W1eff lo
//   [1048576,1179648) W2 hi | [1179648,1310720) W2 lo
// W1eff cols 256:512 overwritten by prep_fold with E = W1b·Wm (permuted).
// f32 bias block (2304): bqkv[768] | bm[256] | geff[512] | beff[512] | b2[256]
// ---------------------------------------------------------------------------
__global__ void prep_weights(const float* __restrict__ Wq, const float* __restrict__ bq,
                             const float* __restrict__ Wk, const float* __restrict__ bk,
                             const float* __restrict__ Wv, const float* __restrict__ bv,
                             const float* __restrict__ Wm, const float* __restrict__ bm,
                             const float* __restrict__ W1, const float* __restrict__ b1,
                             const float* __restrict__ gm, const float* __restrict__ bt,
                             const float* __restrict__ W2, const float* __restrict__ b2,
                             bf16* __restrict__ Wbf, float* __restrict__ bias)
{
  int l = blockIdx.y;
  bf16* wl = Wbf + (size_t)l * 1310720;
  float* bl = bias + l * 2304;
  int j = blockIdx.x * blockDim.x + threadIdx.x;
  if (j >= 592128) return;
  const float INV = 1.0f / sqrtf(1.0f + 1e-5f);
  const float Cs = 0.18033688011112042f;  // log2(e)/8

  float w;
  size_t oh, ol;
  if (j < 196608) {                           // Wqkv, permuted rows
    int t = j >> 16;
    int p = (j >> 8) & 255;
    int k = j & 255;
    int c = ((p & 63) << 2) | (p >> 6);       // p = h*64+i -> c = i*4+h
    const float* W = (t == 0) ? Wq : (t == 1) ? Wk : Wv;
    w = W[(size_t)l * 65536 + c * 256 + k];
    if (t == 0) w *= Cs;
    oh = j; ol = j + 196608;
  } else if (j < 458752) {                    // W1 (msg-cols overwritten by fold)
    int j2 = j - 196608;
    w = W1[(size_t)l * 262144 + j2];
    oh = 524288 + j2; ol = 786432 + j2;
  } else if (j < 589824) {                    // W2
    int j3 = j - 458752;
    w = W2[(size_t)l * 131072 + j3];
    oh = 1048576 + j3; ol = 1179648 + j3;
  } else {                                    // bias
    int b = j - 589824;
    if (b < 768) {
      int t = b >> 8, p = b & 255;
      int c = ((p & 63) << 2) | (p >> 6);
      const float* bsrc = (t == 0) ? bq : (t == 1) ? bk : bv;
      bl[b] = bsrc[l * 256 + c] * ((t == 0) ? Cs : 1.0f);
    } else if (b < 1024) {
      bl[b] = bm[l * 256 + (b - 768)];
    } else if (b < 1536) {
      bl[b] = gm[l * 512 + (b - 1024)] * INV;
    } else if (b < 2048) {
      int o = b - 1536;
      bl[b] = gm[l * 512 + o] * INV * b1[l * 512 + o] + bt[l * 512 + o];
    } else {
      bl[b] = b2[l * 256 + (b - 2048)];
    }
    return;
  }
  unsigned short hi = f2bf(w);
  wl[oh] = hi;
  wl[ol] = f2bf(w - bf2f(hi));
}

// ---------------------------------------------------------------------------
// Merge-GEMM fold (coalesced): E'[r][k] = sum_oc W1b[r][oc]*Wm[oc][k], stored
// at permuted col p = ((k&3)<<6)|(k>>2); beff[r] += geff[r]*(W1b·bm)[r].
// ---------------------------------------------------------------------------
__global__ void prep_fold(const float* __restrict__ W1, const float* __restrict__ Wm,
                          const float* __restrict__ bm,
                          bf16* __restrict__ Wbf, float* __restrict__ bias)
{
  int l = blockIdx.y;
  int r0 = blockIdx.x * 8;
  int k = threadIdx.x;
  __shared__ float w1b[8][256];
  for (int j = threadIdx.x; j < 2048; j += 256)
    w1b[j >> 8][j & 255] = W1[(size_t)l * 262144 + (r0 + (j >> 8)) * 512 + 256 + (j & 255)];
  __syncthreads();
  float acc[8] = {0.f, 0.f, 0.f, 0.f, 0.f, 0.f, 0.f, 0.f};
  const float* wmrow = Wm + (size_t)l * 65536 + k;
  for (int oc = 0; oc < 256; oc++) {
    float wv = wmrow[oc * 256];               // coalesced across threads
    #pragma unroll
    for (int j = 0; j < 8; j++) acc[j] += w1b[j][oc] * wv;  // LDS broadcast
  }
  int p = ((k & 3) << 6) | (k >> 2);          // inv-perm: perm(p) == k
  bf16* wl = Wbf + (size_t)l * 1310720;
  #pragma unroll
  for (int j = 0; j < 8; j++) {
    unsigned short hi = f2bf(acc[j]);
    wl[524288 + (size_t)(r0 + j) * 512 + 256 + p] = hi;
    wl[786432 + (size_t)(r0 + j) * 512 + 256 + p] = f2bf(acc[j] - bf2f(hi));
  }
  if (threadIdx.x < 8) {
    int j = threadIdx.x;
    float d = 0.f;
    for (int oc = 0; oc < 256; oc++) d += w1b[j][oc] * bm[l * 256 + oc];
    float ge = bias[l * 2304 + 1024 + r0 + j];
    bias[l * 2304 + 1536 + r0 + j] += ge * d;   // unique writer per row
  }
}

// ---------------------------------------------------------------------------
__global__ void transpose_in(const float* __restrict__ s0, const float* __restrict__ s1,
                             float* __restrict__ Dm, bf16* __restrict__ Hin,
                             bf16* __restrict__ XMl)
{
  __shared__ float t[32][33];
  int db = blockIdx.z;
  int dsc = db >> 1, bi = db & 1;
  const float* src = dsc ? s1 : s0;
  int n0 = blockIdx.x * 32, d0 = blockIdx.y * 32;
  int tx = threadIdx.x, ty = threadIdx.y;
  #pragma unroll
  for (int i = 0; i < 32; i += 8)
    t[ty + i][tx] = src[(size_t)(bi * 256 + d0 + ty + i) * 2048 + n0 + tx];
  __syncthreads();
  #pragma unroll
  for (int i = 0; i < 32; i += 8) {
    size_t xi = (size_t)db * 2048 + n0 + ty + i;
    float v = t[tx][ty + i];
    Dm[xi * 256 + d0 + tx] = v;
    unsigned short hi, lo;
    tsplit(v, hi, lo);
    Hin[xi * 512 + d0 + tx] = hi;
    XMl[xi * 512 + d0 + tx] = lo;
  }
}

__global__ void transpose_out(const float* __restrict__ Dm, float* __restrict__ out)
{
  __shared__ float t[32][33];
  int db = blockIdx.z;
  int n0 = blockIdx.x * 32, d0 = blockIdx.y * 32;
  int tx = threadIdx.x, ty = threadIdx.y;
  #pragma unroll
  for (int i = 0; i < 32; i += 8)
    t[ty + i][tx] = Dm[((size_t)db * 2048 + n0 + ty + i) * 256 + d0 + tx];
  __syncthreads();
  #pragma unroll
  for (int i = 0; i < 32; i += 8)
    out[(size_t)(db * 256 + d0 + ty + i) * 2048 + n0 + tx] = t[tx][ty + i];
}

// ---------------------------------------------------------------------------
// 3-term split GEMM (round-17 structure): tile 64xNT, BK=32, 4 waves
// (2x2 of 32 x NT/2), double-buffered global_load_lds, counted vmcnt + raw
// bars, sigma-swizzle gsw2 (coalesced staging quads + conflict-free reads).
// ---------------------------------------------------------------------------
DEVFN int gsw2(int row, int g) { return row * 32 + (((g ^ (row >> 1)) & 3) << 3); }

template<int EPI, int NT>
__global__ __launch_bounds__(256, 3) void gemm3(
    const bf16* __restrict__ Ah, int lda,
    const bf16* __restrict__ Al, int ldal,
    const bf16* __restrict__ Wh, const bf16* __restrict__ Wl, int K,
    const float* __restrict__ b0, const float* __restrict__ b1,
    bf16* __restrict__ o0, bf16* __restrict__ o1,
    bf16* __restrict__ o2, bf16* __restrict__ o3,
    bf16* __restrict__ o4, bf16* __restrict__ o5,
    float* __restrict__ of)
{
  constexpr int NFR = NT / 32;
  __shared__ bf16 AsH[2][2048];
  __shared__ bf16 AsL[2][2048];
  __shared__ bf16 BsH[2][NT * 32];
  __shared__ bf16 BsL[2][NT * 32];
  int tid = threadIdx.x, lane = tid & 63, wid = tid >> 6;
  int wr = wid >> 1, wc = wid & 1;
  int m0 = blockIdx.x * 64, n0 = blockIdx.y * NT;

  int lrow = lane >> 2;
  int g4 = (((lane & 3) ^ (lane >> 3)) & 3) << 3;
  const bf16* A0h = Ah + (size_t)(m0 + wid * 16 + lrow) * lda + g4;
  const bf16* A0l = Al + (size_t)(m0 + wid * 16 + lrow) * ldal + g4;
  const bf16* B0h = Wh + (size_t)(n0 + wid * 16 + lrow) * K + g4;
  const bf16* B0l = Wl + (size_t)(n0 + wid * 16 + lrow) * K + g4;
  size_t b64 = (size_t)64 * K;

  auto issue = [&](int k0, int b) {
    gll16(A0h + k0, &AsH[b][wid * 512]);
    gll16(A0l + k0, &AsL[b][wid * 512]);
    gll16(B0h + k0, &BsH[b][wid * 512]);
    gll16(B0l + k0, &BsL[b][wid * 512]);
    if constexpr (NT == 128) {
      gll16(B0h + b64 + k0, &BsH[b][2048 + wid * 512]);
      gll16(B0l + b64 + k0, &BsL[b][2048 + wid * 512]);
    }
  };

  f32x4 zero = {0.f, 0.f, 0.f, 0.f};
  f32x4 acc[2][NFR];
  #pragma unroll
  for (int i = 0; i < 2; i++)
    #pragma unroll
    for (int j = 0; j < NFR; j++) acc[i][j] = zero;

  int fr = lane & 15, g = lane >> 4;
  int cb = wc * (NT / 2);
  int nk = K >> 5;

  issue(0, 0);
  for (int ks = 0; ks < nk; ks++) {
    int cur = ks & 1;
    if (ks + 1 < nk) {
      issue((ks + 1) << 5, cur ^ 1);
      if constexpr (NT == 128) VMW(6); else VMW(4);   // waits exactly issue(ks)
    } else {
      VMW(0);
    }
    RBAR(); SCHB();
    bf16x8 afh[2], afl[2], bfh[NFR], bfl[NFR];
    #pragma unroll
    for (int i = 0; i < 2; i++) {
      afh[i] = *(const bf16x8*)(&AsH[cur][gsw2(wr * 32 + i * 16 + fr, g)]);
      afl[i] = *(const bf16x8*)(&AsL[cur][gsw2(wr * 32 + i * 16 + fr, g)]);
    }
    #pragma unroll
    for (int i = 0; i < NFR; i++) {
      bfh[i] = *(const bf16x8*)(&BsH[cur][gsw2(cb + i * 16 + fr, g)]);
      bfl[i] = *(const bf16x8*)(&BsL[cur][gsw2(cb + i * 16 + fr, g)]);
    }
    #pragma unroll
    for (int mi = 0; mi < 2; mi++)
      #pragma unroll
      for (int ni = 0; ni < NFR; ni++) {
        acc[mi][ni] = MFMA_BF16(afh[mi], bfh[ni], acc[mi][ni]);
        acc[mi][ni] = MFMA_BF16(afl[mi], bfh[ni], acc[mi][ni]);
        acc[mi][ni] = MFMA_BF16(afh[mi], bfl[ni], acc[mi][ni]);
      }
    RBAR();
  }

  #pragma unroll
  for (int mi = 0; mi < 2; mi++) {
    #pragma unroll
    for (int ni = 0; ni < NFR; ni++) {
      int mrow = m0 + wr * 32 + mi * 16 + ((lane >> 4) << 2);
      int ocol = n0 + cb + ni * 16 + fr;
      if constexpr (EPI == 0) {          // fused QKV
        float bb = b0[ocol];
        if (ocol < 512) {
          bf16* Dh = (ocol < 256) ? o0 : o2;
          bf16* Dl = (ocol < 256) ? o1 : o3;
          int oo = ocol & 255;
          #pragma unroll
          for (int r = 0; r < 4; r++) {
            unsigned short hi, lo;
            tsplit(acc[mi][ni][r] + bb, hi, lo);
            Dh[(size_t)(mrow + r) * 256 + oo] = hi;
            Dl[(size_t)(mrow + r) * 256 + oo] = lo;
          }
        } else {
          int c = ocol - 512;
          int dbi = mrow >> 11, nn = mrow & 2047;
          u16x4 ph, pl;
          #pragma unroll
          for (int r = 0; r < 4; r++) {
            unsigned short hi, lo;
            tsplit(acc[mi][ni][r] + bb, hi, lo);
            ph[r] = hi; pl[r] = lo;
          }
          *(u16x4*)(&o4[((size_t)dbi * 256 + c) * 2048 + nn]) = ph;
          *(u16x4*)(&o5[((size_t)dbi * 256 + c) * 2048 + nn]) = pl;
        }
      } else if constexpr (EPI == 3) {   // BN+ReLU hi+lo
        float ge = b0[ocol], be = b1[ocol];
        #pragma unroll
        for (int r = 0; r < 4; r++) {
          unsigned short hi, lo;
          tsplit(fmaxf(ge * acc[mi][ni][r] + be, 0.f), hi, lo);
          o0[(size_t)(mrow + r) * 512 + ocol] = hi;
          o1[(size_t)(mrow + r) * 512 + ocol] = lo;
        }
      } else {                           // EPI 4: residual
        float bb = b0[ocol];
        #pragma unroll
        for (int r = 0; r < 4; r++) {
          size_t ix = (size_t)(mrow + r) * 256 + ocol;
          float d = of[ix] + acc[mi][ni][r] + bb;
          of[ix] = d;
          unsigned short hi, lo;
          tsplit(d, hi, lo);
          o0[(size_t)(mrow + r) * 512 + ocol] = hi;
          o1[(size_t)(mrow + r) * 512 + ocol] = lo;
        }
      }
    }
  }
}

// ---------------------------------------------------------------------------
// Flash attention, Q-SPLIT (no combine): grid (32 Q-blocks, 16 inst), 256 thr
// (4 waves x 16 q-rows = QB 64), 32 KV tiles. Swapped QK^T (S[key][q=lane&15],
// per-lane softmax scalars), b64-packed P-store, 3-phase pipeline, defer-max.
// Each wave stages 16 K/V rows (two 8-row chunks). O normalized in-kernel,
// written directly into Hin/XMl cols 256:512.
// ---------------------------------------------------------------------------
DEVFN int swz(int row, int col) { return row * 64 + (col ^ ((row & 7) << 3)); }

__global__ __launch_bounds__(256, 4) void attn3s(
    const bf16* __restrict__ Qh, const bf16* __restrict__ Ql,
    const bf16* __restrict__ Kh, const bf16* __restrict__ Kl,
    const bf16* __restrict__ Vth, const bf16* __restrict__ Vtl,
    bf16* __restrict__ Hin, bf16* __restrict__ XMl, int cross)
{
  __shared__ bf16 Ksh[64 * 64];
  __shared__ bf16 Ksl[64 * 64];
  __shared__ bf16 Vsh[64 * 64];
  __shared__ bf16 Vsl[64 * 64];
  __shared__ bf16 Psh[4][1024];
  __shared__ bf16 Psl[4][1024];
  int tid = threadIdx.x, lane = tid & 63, w = tid >> 6;   // 4 waves
  int inst = blockIdx.y;
  int db = inst >> 2, hd = inst & 3;
  int dsc = db >> 1, bi = db & 1;
  int sdb = (cross ? (1 - dsc) : dsc) * 2 + bi;
  size_t xq = (size_t)db * 2048;
  size_t xs = (size_t)sdb * 2048;
  int n0 = blockIdx.x * 64;

  int fr = lane & 15, g = lane >> 4, kof = g << 3;

  // Q fragments hi/lo: direct global -> registers (row q = n0 + w*16 + fr)
  bf16x8 aqh[2], aql[2];
  #pragma unroll
  for (int kf = 0; kf < 2; kf++) {
    size_t gx = (xq + n0 + w * 16 + fr) * 256 + hd * 64 + kf * 32 + kof;
    aqh[kf] = *(const bf16x8*)(Qh + gx);
    aql[kf] = *(const bf16x8*)(Ql + gx);
  }

  f32x4 zero = {0.f, 0.f, 0.f, 0.f};
  f32x4 oacc[4];
  #pragma unroll
  for (int ni = 0; ni < 4; ni++) oacc[ni] = zero;
  float mrun = -3.0e38f, lrun = 0.f;   // per-lane: q = lane&15

  // staging: wave w covers K/V rows w*16 .. w*16+15 in two 8-row chunks
  int lrow = lane >> 3;                 // 0..7
  int g8 = ((lane & 7) ^ (lrow & 7)) << 3;
  int kr = w * 16 + lrow;
  const bf16* Ksrc_h = Kh + (xs + kr) * 256 + hd * 64 + g8;
  const bf16* Ksrc_l = Kl + (xs + kr) * 256 + hd * 64 + g8;
  const bf16* Vsrc_h = Vth + ((size_t)sdb * 256 + hd * 64 + kr) * 2048 + g8;
  const bf16* Vsrc_l = Vtl + ((size_t)sdb * 256 + hd * 64 + kr) * 2048 + g8;
  bf16* LKh = Ksh + w * 1024;
  bf16* LKl = Ksl + w * 1024;
  bf16* LVh = Vsh + w * 1024;
  bf16* LVl = Vsl + w * 1024;

  auto issueK = [&](int t) {
    gll16(Ksrc_h + (size_t)t * 16384, LKh);
    gll16(Ksrc_h + (size_t)t * 16384 + 2048, LKh + 512);   // +8 rows
    gll16(Ksrc_l + (size_t)t * 16384, LKl);
    gll16(Ksrc_l + (size_t)t * 16384 + 2048, LKl + 512);
  };
  auto issueV = [&](int t) {
    gll16(Vsrc_h + t * 64, LVh);
    gll16(Vsrc_h + (size_t)8 * 2048 + t * 64, LVh + 512);  // +8 rows
    gll16(Vsrc_l + t * 64, LVl);
    gll16(Vsrc_l + (size_t)8 * 2048 + t * 64, LVl + 512);
  };

  issueK(0);
  issueV(0);

  for (int t = 0; t < 32; t++) {
    VMW(4);            // K(t) landed; 4 V(t) loads stay in flight
    RBAR(); SCHB();

    // ---- QK^T swapped: sacc[ni] = S[key = ni*16+4g+r][q = fr] ----
    f32x4 sacc[4];
    #pragma unroll
    for (int ni = 0; ni < 4; ni++) sacc[ni] = zero;
    #pragma unroll
    for (int kf = 0; kf < 2; kf++) {
      #pragma unroll
      for (int ni = 0; ni < 4; ni++) {
        bf16x8 bkh = *(const bf16x8*)(&Ksh[swz(ni * 16 + fr, kf * 32 + kof)]);
        bf16x8 bkl = *(const bf16x8*)(&Ksl[swz(ni * 16 + fr, kf * 32 + kof)]);
        sacc[ni] = MFMA_BF16(bkh, aqh[kf], sacc[ni]);
        sacc[ni] = MFMA_BF16(bkh, aql[kf], sacc[ni]);
        sacc[ni] = MFMA_BF16(bkl, aqh[kf], sacc[ni]);
      }
    }

    // ---- softmax, q local per lane: cheap defer-max check ----
    float tml = fmaxf(fmaxf(fmaxf(sacc[0][0], sacc[0][1]), fmaxf(sacc[0][2], sacc[0][3])),
               fmaxf(fmaxf(fmaxf(sacc[1][0], sacc[1][1]), fmaxf(sacc[1][2], sacc[1][3])),
               fmaxf(fmaxf(fmaxf(sacc[2][0], sacc[2][1]), fmaxf(sacc[2][2], sacc[2][3])),
                     fmaxf(fmaxf(sacc[3][0], sacc[3][1]), fmaxf(sacc[3][2], sacc[3][3])))));
    bool need = (tml > mrun + 8.0f);
    if (__ballot(need)) {
      float tm = fmaxf(tml, __shfl_xor(tml, 16));
      tm = fmaxf(tm, __shfl_xor(tm, 32));
      float mn = fmaxf(mrun, tm);
      float s = exp2f(mrun - mn);
      mrun = mn;
      lrun *= s;
      // oacc rows are q' = 4g + r; fetch s(q') from lane q' (group 0)
      #pragma unroll
      for (int r = 0; r < 4; r++) {
        float sr = __shfl(s, (g << 2) + r);
        #pragma unroll
        for (int ni = 0; ni < 4; ni++) oacc[ni][r] *= sr;
      }
    }
    float sum = 0.f;
    #pragma unroll
    for (int ni = 0; ni < 4; ni++)
      #pragma unroll
      for (int r = 0; r < 4; r++) {
        float pv = exp2f(sacc[ni][r] - mrun);
        sacc[ni][r] = pv;
        sum += pv;
      }
    sum += __shfl_xor(sum, 16);
    sum += __shfl_xor(sum, 32);
    lrun += sum;

    VMW(0);            // V(t) landed
    RBAR(); SCHB();    // all waves finished QK^T -> K LDS free

    if (t + 1 < 32) issueK(t + 1);   // flies under P-store + PV

    // ---- P -> LDS, [q][key] layout, b64 packed (keys 4g..4g+3) ----
    bf16* Pwh = &Psh[w][0];
    bf16* Pwl = &Psl[w][0];
    #pragma unroll
    for (int ni = 0; ni < 4; ni++) {
      u16x4 ph, pl;
      #pragma unroll
      for (int r = 0; r < 4; r++) {
        unsigned short h0, l0;
        tsplit(sacc[ni][r], h0, l0);
        ph[r] = h0; pl[r] = l0;
      }
      int off = swz(fr, ni * 16 + (g << 2));   // 4-aligned col -> 8B aligned
      *(u16x4*)(&Pwh[off]) = ph;
      *(u16x4*)(&Pwl[off]) = pl;
    }

    // ---- PV (3-term); A-frag reads from [q][key] LDS ----
    #pragma unroll
    for (int kf = 0; kf < 2; kf++) {
      bf16x8 pah = *(const bf16x8*)(&Pwh[swz(fr, kf * 32 + kof)]);
      bf16x8 pal = *(const bf16x8*)(&Pwl[swz(fr, kf * 32 + kof)]);
      #pragma unroll
      for (int ni = 0; ni < 4; ni++) {
        bf16x8 bvh = *(const bf16x8*)(&Vsh[swz(ni * 16 + fr, kf * 32 + kof)]);
        bf16x8 bvl = *(const bf16x8*)(&Vsl[swz(ni * 16 + fr, kf * 32 + kof)]);
        oacc[ni] = MFMA_BF16(pah, bvh, oacc[ni]);
        oacc[ni] = MFMA_BF16(pal, bvh, oacc[ni]);
        oacc[ni] = MFMA_BF16(pah, bvl, oacc[ni]);
      }
    }

    RBAR();            // all waves done PV -> V LDS free
    if (t + 1 < 32) issueV(t + 1);   // flies under next QK^T + softmax
  }

  // normalize + write O hi/lo directly into Hin/XMl cols 256:512
  float inv = 1.0f / lrun;             // valid for q = fr on every lane
  #pragma unroll
  for (int r = 0; r < 4; r++) {
    float rinv = __shfl(inv, (g << 2) + r);   // inv for row q' = 4g + r
    size_t row = xq + n0 + w * 16 + (g << 2) + r;
    #pragma unroll
    for (int ni = 0; ni < 4; ni++) {
      unsigned short hi, lo;
      tsplit(oacc[ni][r] * rinv, hi, lo);
      size_t gx = row * 512 + 256 + hd * 64 + ni * 16 + fr;
      Hin[gx] = hi;
      XMl[gx] = lo;
    }
  }
}

// ---------------------------------------------------------------------------
extern "C" void kernel_launch(void* const* d_in, const int* in_sizes, int n_in,
                              void* d_out, int out_size, void* d_ws, size_t ws_size,
                              hipStream_t stream)
{
  (void)in_sizes; (void)n_in; (void)out_size; (void)ws_size;
  const float* desc0 = (const float*)d_in[0];
  const float* desc1 = (const float*)d_in[1];
  const float* Wq = (const float*)d_in[2];
  const float* bq = (const float*)d_in[3];
  const float* Wk = (const float*)d_in[4];
  const float* bk = (const float*)d_in[5];
  const float* Wv = (const float*)d_in[6];
  const float* bv = (const float*)d_in[7];
  const float* Wm = (const float*)d_in[8];
  const float* bm = (const float*)d_in[9];
  const float* W1 = (const float*)d_in[10];
  const float* b1 = (const float*)d_in[11];
  const float* gm = (const float*)d_in[12];
  const float* bt = (const float*)d_in[13];
  const float* W2 = (const float*)d_in[14];
  const float* b2 = (const float*)d_in[15];
  float* out = (float*)d_out;

  char* ws = (char*)d_ws;
  bf16*  Wbf  = (bf16*)(ws + 0);            //  31,457,280
  float* bias = (float*)(ws + 31457280);    //     110,592
  float* Dm   = (float*)(ws + 31567872);    //  16,777,216  fp32 master [xi,256]
  bf16*  Hin  = (bf16*)(ws + 48345088);     //  16,777,216  [xi,512] = xh | O_h
  bf16*  XMl  = (bf16*)(ws + 65122304);     //  16,777,216  [xi,512] = xl | O_l
  bf16*  Qh   = (bf16*)(ws + 81899520);     //   8,388,608
  bf16*  Ql   = (bf16*)(ws + 90288128);     //   8,388,608
  bf16*  Kh   = (bf16*)(ws + 98676736);     //   8,388,608
  bf16*  Kl   = (bf16*)(ws + 107065344);    //   8,388,608
  bf16*  Vth  = (bf16*)(ws + 115453952);    //   8,388,608  [db,256,2048]
  bf16*  Vtl  = (bf16*)(ws + 123842560);    //   8,388,608  -> end 132,231,168
  bf16*  Hbh  = Qh;                         // alias Qh+Ql (disjoint in time)
  bf16*  Hbl  = Kh;                         // alias Kh+Kl

  prep_weights<<<dim3(2313, 12), 256, 0, stream>>>(Wq, bq, Wk, bk, Wv, bv, Wm, bm,
                                                   W1, b1, gm, bt, W2, b2, Wbf, bias);
  prep_fold<<<dim3(64, 12), 256, 0, stream>>>(W1, Wm, bm, Wbf, bias);
  transpose_in<<<dim3(64, 8, 4), dim3(32, 8), 0, stream>>>(desc0, desc1, Dm, Hin, XMl);

  for (int l = 0; l < NL; l++) {
    const bf16* wl = Wbf + (size_t)l * 1310720;
    const float* bl = bias + l * 2304;
    int cross = l & 1;
    // fused QKV (Q pre-scaled by log2e/8): 768 blocks = 3/CU
    gemm3<0, 128><<<dim3(128, 6), 256, 0, stream>>>(Hin, 512, XMl, 512,
        wl, wl + 196608, 256, bl, nullptr,
        Qh, Ql, Kh, Kl, Vth, Vtl, nullptr);
    // Q-split attention (writes normalized O into Hin/XMl msg-half): 512 blocks
    attn3s<<<dim3(32, 16), 256, 0, stream>>>(Qh, Ql, Kh, Kl, Vth, Vtl,
                                             Hin, XMl, cross);
    // MLP1 (merge folded in): 512 blocks = 2/CU
    gemm3<3, 128><<<dim3(128, 4), 256, 0, stream>>>(Hin, 512, XMl, 512,
        wl + 524288, wl + 786432, 512, bl + 1024, bl + 1536,
        Hbh, Hbl, nullptr, nullptr, nullptr, nullptr, nullptr);
    // MLP2 + residual: 512 blocks = 2/CU
    gemm3<4, 64><<<dim3(128, 4), 256, 0, stream>>>(Hbh, 512, Hbl, 512,
        wl + 1048576, wl + 1179648, 512, bl + 2048, nullptr,
        Hin, XMl, nullptr, nullptr, nullptr, nullptr, Dm);
  }
  transpose_out<<<dim3(64, 8, 4), dim3(32, 8), 0, stream>>>(Dm, out);
}

// Round 19
// 1451.033 us; speedup vs baseline: 1.0855x; 1.0855x over previous
//
#include <hip/hip_runtime.h>

typedef unsigned short bf16;
typedef __attribute__((ext_vector_type(8))) short bf16x8;
typedef __attribute__((ext_vector_type(4))) float f32x4;
typedef unsigned short u16x4 __attribute__((ext_vector_type(4)));

#define DEVFN static __device__ __forceinline__

#define NL 12

#define VMW(N) asm volatile("s_waitcnt vmcnt(" #N ")" ::: "memory")
#define RBAR() asm volatile("s_barrier" ::: "memory")
#define SCHB() __builtin_amdgcn_sched_barrier(0)

DEVFN unsigned short f2bf(float f) {
  union { float f; unsigned u; } v; v.f = f;
  unsigned u = v.u;
  unsigned r = (u + 0x7fffu + ((u >> 16) & 1u)) >> 16;  // RNE
  return (unsigned short)r;
}
DEVFN float bf2f(unsigned short h) {
  union { unsigned u; float f; } v; v.u = ((unsigned)h) << 16; return v.f;
}
// truncation hi/lo split: 4 ALU ops, pair error ~2^-18
DEVFN void tsplit(float v, unsigned short& h, unsigned short& l) {
  union { float f; unsigned u; } a; a.f = v;
  h = (unsigned short)(a.u >> 16);
  union { float f; unsigned u; } b; b.u = a.u & 0xffff0000u;
  union { float f; unsigned u; } c; c.f = v - b.f;
  l = (unsigned short)(c.u >> 16);
}
// async global->LDS, 16B per lane; dest = wave-uniform base + lane*16
DEVFN void gll16(const bf16* g, bf16* l) {
  __builtin_amdgcn_global_load_lds(
      (const __attribute__((address_space(1))) unsigned int*)g,
      (__attribute__((address_space(3))) unsigned int*)l, 16, 0, 0);
}

#define MFMA_BF16(a, b, c) __builtin_amdgcn_mfma_f32_16x16x32_bf16((a), (b), (c), 0, 0, 0)

// ---------------------------------------------------------------------------
// Weight prep v2: one thread per WEIGHT ELEMENT (hi+lo computed together).
// Wq/bq folded with Cs = log2(e)/8. Per-layer bf16 block (1310720):
//   [0,196608) Wqkv hi | [196608,393216) Wqkv lo | [393216,524288) unused
//   [524288,786432) W1eff hi | [786432,1048576) W1eff lo
//   [1048576,1179648) W2 hi | [1179648,1310720) W2 lo
// W1eff cols 256:512 overwritten by prep_fold with E = W1b·Wm (permuted).
// f32 bias block (2304): bqkv[768] | bm[256] | geff[512] | beff[512] | b2[256]
// ---------------------------------------------------------------------------
__global__ void prep_weights(const float* __restrict__ Wq, const float* __restrict__ bq,
                             const float* __restrict__ Wk, const float* __restrict__ bk,
                             const float* __restrict__ Wv, const float* __restrict__ bv,
                             const float* __restrict__ Wm, const float* __restrict__ bm,
                             const float* __restrict__ W1, const float* __restrict__ b1,
                             const float* __restrict__ gm, const float* __restrict__ bt,
                             const float* __restrict__ W2, const float* __restrict__ b2,
                             bf16* __restrict__ Wbf, float* __restrict__ bias)
{
  int l = blockIdx.y;
  bf16* wl = Wbf + (size_t)l * 1310720;
  float* bl = bias + l * 2304;
  int j = blockIdx.x * blockDim.x + threadIdx.x;
  if (j >= 592128) return;
  const float INV = 1.0f / sqrtf(1.0f + 1e-5f);
  const float Cs = 0.18033688011112042f;  // log2(e)/8

  float w;
  size_t oh, ol;
  if (j < 196608) {                           // Wqkv, permuted rows
    int t = j >> 16;
    int p = (j >> 8) & 255;
    int k = j & 255;
    int c = ((p & 63) << 2) | (p >> 6);       // p = h*64+i -> c = i*4+h
    const float* W = (t == 0) ? Wq : (t == 1) ? Wk : Wv;
    w = W[(size_t)l * 65536 + c * 256 + k];
    if (t == 0) w *= Cs;
    oh = j; ol = j + 196608;
  } else if (j < 458752) {                    // W1 (msg-cols overwritten by fold)
    int j2 = j - 196608;
    w = W1[(size_t)l * 262144 + j2];
    oh = 524288 + j2; ol = 786432 + j2;
  } else if (j < 589824) {                    // W2
    int j3 = j - 458752;
    w = W2[(size_t)l * 131072 + j3];
    oh = 1048576 + j3; ol = 1179648 + j3;
  } else {                                    // bias
    int b = j - 589824;
    if (b < 768) {
      int t = b >> 8, p = b & 255;
      int c = ((p & 63) << 2) | (p >> 6);
      const float* bsrc = (t == 0) ? bq : (t == 1) ? bk : bv;
      bl[b] = bsrc[l * 256 + c] * ((t == 0) ? Cs : 1.0f);
    } else if (b < 1024) {
      bl[b] = bm[l * 256 + (b - 768)];
    } else if (b < 1536) {
      bl[b] = gm[l * 512 + (b - 1024)] * INV;
    } else if (b < 2048) {
      int o = b - 1536;
      bl[b] = gm[l * 512 + o] * INV * b1[l * 512 + o] + bt[l * 512 + o];
    } else {
      bl[b] = b2[l * 256 + (b - 2048)];
    }
    return;
  }
  unsigned short hi = f2bf(w);
  wl[oh] = hi;
  wl[ol] = f2bf(w - bf2f(hi));
}

// ---------------------------------------------------------------------------
// Merge-GEMM fold (coalesced): E'[r][k] = sum_oc W1b[r][oc]*Wm[oc][k], stored
// at permuted col p = ((k&3)<<6)|(k>>2); beff[r] += geff[r]*(W1b·bm)[r].
// ---------------------------------------------------------------------------
__global__ void prep_fold(const float* __restrict__ W1, const float* __restrict__ Wm,
                          const float* __restrict__ bm,
                          bf16* __restrict__ Wbf, float* __restrict__ bias)
{
  int l = blockIdx.y;
  int r0 = blockIdx.x * 8;
  int k = threadIdx.x;
  __shared__ float w1b[8][256];
  for (int j = threadIdx.x; j < 2048; j += 256)
    w1b[j >> 8][j & 255] = W1[(size_t)l * 262144 + (r0 + (j >> 8)) * 512 + 256 + (j & 255)];
  __syncthreads();
  float acc[8] = {0.f, 0.f, 0.f, 0.f, 0.f, 0.f, 0.f, 0.f};
  const float* wmrow = Wm + (size_t)l * 65536 + k;
  for (int oc = 0; oc < 256; oc++) {
    float wv = wmrow[oc * 256];               // coalesced across threads
    #pragma unroll
    for (int j = 0; j < 8; j++) acc[j] += w1b[j][oc] * wv;  // LDS broadcast
  }
  int p = ((k & 3) << 6) | (k >> 2);          // inv-perm: perm(p) == k
  bf16* wl = Wbf + (size_t)l * 1310720;
  #pragma unroll
  for (int j = 0; j < 8; j++) {
    unsigned short hi = f2bf(acc[j]);
    wl[524288 + (size_t)(r0 + j) * 512 + 256 + p] = hi;
    wl[786432 + (size_t)(r0 + j) * 512 + 256 + p] = f2bf(acc[j] - bf2f(hi));
  }
  if (threadIdx.x < 8) {
    int j = threadIdx.x;
    float d = 0.f;
    for (int oc = 0; oc < 256; oc++) d += w1b[j][oc] * bm[l * 256 + oc];
    float ge = bias[l * 2304 + 1024 + r0 + j];
    bias[l * 2304 + 1536 + r0 + j] += ge * d;   // unique writer per row
  }
}

// ---------------------------------------------------------------------------
__global__ void transpose_in(const float* __restrict__ s0, const float* __restrict__ s1,
                             float* __restrict__ Dm, bf16* __restrict__ Hin,
                             bf16* __restrict__ XMl)
{
  __shared__ float t[32][33];
  int db = blockIdx.z;
  int dsc = db >> 1, bi = db & 1;
  const float* src = dsc ? s1 : s0;
  int n0 = blockIdx.x * 32, d0 = blockIdx.y * 32;
  int tx = threadIdx.x, ty = threadIdx.y;
  #pragma unroll
  for (int i = 0; i < 32; i += 8)
    t[ty + i][tx] = src[(size_t)(bi * 256 + d0 + ty + i) * 2048 + n0 + tx];
  __syncthreads();
  #pragma unroll
  for (int i = 0; i < 32; i += 8) {
    size_t xi = (size_t)db * 2048 + n0 + ty + i;
    float v = t[tx][ty + i];
    Dm[xi * 256 + d0 + tx] = v;
    unsigned short hi, lo;
    tsplit(v, hi, lo);
    Hin[xi * 512 + d0 + tx] = hi;
    XMl[xi * 512 + d0 + tx] = lo;
  }
}

__global__ void transpose_out(const float* __restrict__ Dm, float* __restrict__ out)
{
  __shared__ float t[32][33];
  int db = blockIdx.z;
  int n0 = blockIdx.x * 32, d0 = blockIdx.y * 32;
  int tx = threadIdx.x, ty = threadIdx.y;
  #pragma unroll
  for (int i = 0; i < 32; i += 8)
    t[ty + i][tx] = Dm[((size_t)db * 2048 + n0 + ty + i) * 256 + d0 + tx];
  __syncthreads();
  #pragma unroll
  for (int i = 0; i < 32; i += 8)
    out[(size_t)(db * 256 + d0 + ty + i) * 2048 + n0 + tx] = t[tx][ty + i];
}

// ---------------------------------------------------------------------------
// 3-term split GEMM, tile 64xNT (BM=64 for grid occupancy: 512-768 blocks =
// 2-3/CU), BK=32, 4 waves (2x2 of 32 x NT/2). Double-buffered global_load_lds,
// counted vmcnt + raw bars, sigma-swizzle gsw2 (coalesced staging quads +
// conflict-free reads). Per issue: A 2 loads, B 4 (NT=128) / 2 (NT=64).
// ---------------------------------------------------------------------------
DEVFN int gsw2(int row, int g) { return row * 32 + (((g ^ (row >> 1)) & 3) << 3); }

template<int EPI, int NT>
__global__ __launch_bounds__(256, 3) void gemm3(
    const bf16* __restrict__ Ah, int lda,
    const bf16* __restrict__ Al, int ldal,
    const bf16* __restrict__ Wh, const bf16* __restrict__ Wl, int K,
    const float* __restrict__ b0, const float* __restrict__ b1,
    bf16* __restrict__ o0, bf16* __restrict__ o1,
    bf16* __restrict__ o2, bf16* __restrict__ o3,
    bf16* __restrict__ o4, bf16* __restrict__ o5,
    float* __restrict__ of)
{
  constexpr int NFR = NT / 32;
  __shared__ bf16 AsH[2][2048];
  __shared__ bf16 AsL[2][2048];
  __shared__ bf16 BsH[2][NT * 32];
  __shared__ bf16 BsL[2][NT * 32];
  int tid = threadIdx.x, lane = tid & 63, wid = tid >> 6;
  int wr = wid >> 1, wc = wid & 1;
  int m0 = blockIdx.x * 64, n0 = blockIdx.y * NT;

  int lrow = lane >> 2;
  int g4 = (((lane & 3) ^ (lane >> 3)) & 3) << 3;
  const bf16* A0h = Ah + (size_t)(m0 + wid * 16 + lrow) * lda + g4;
  const bf16* A0l = Al + (size_t)(m0 + wid * 16 + lrow) * ldal + g4;
  const bf16* B0h = Wh + (size_t)(n0 + wid * 16 + lrow) * K + g4;
  const bf16* B0l = Wl + (size_t)(n0 + wid * 16 + lrow) * K + g4;
  size_t b64 = (size_t)64 * K;

  auto issue = [&](int k0, int b) {
    gll16(A0h + k0, &AsH[b][wid * 512]);
    gll16(A0l + k0, &AsL[b][wid * 512]);
    gll16(B0h + k0, &BsH[b][wid * 512]);
    gll16(B0l + k0, &BsL[b][wid * 512]);
    if constexpr (NT == 128) {
      gll16(B0h + b64 + k0, &BsH[b][2048 + wid * 512]);
      gll16(B0l + b64 + k0, &BsL[b][2048 + wid * 512]);
    }
  };

  f32x4 zero = {0.f, 0.f, 0.f, 0.f};
  f32x4 acc[2][NFR];
  #pragma unroll
  for (int i = 0; i < 2; i++)
    #pragma unroll
    for (int j = 0; j < NFR; j++) acc[i][j] = zero;

  int fr = lane & 15, g = lane >> 4;
  int cb = wc * (NT / 2);
  int nk = K >> 5;

  issue(0, 0);
  for (int ks = 0; ks < nk; ks++) {
    int cur = ks & 1;
    if (ks + 1 < nk) {
      issue((ks + 1) << 5, cur ^ 1);
      if constexpr (NT == 128) VMW(6); else VMW(4);   // waits exactly issue(ks)
    } else {
      VMW(0);
    }
    RBAR(); SCHB();
    bf16x8 afh[2], afl[2], bfh[NFR], bfl[NFR];
    #pragma unroll
    for (int i = 0; i < 2; i++) {
      afh[i] = *(const bf16x8*)(&AsH[cur][gsw2(wr * 32 + i * 16 + fr, g)]);
      afl[i] = *(const bf16x8*)(&AsL[cur][gsw2(wr * 32 + i * 16 + fr, g)]);
    }
    #pragma unroll
    for (int i = 0; i < NFR; i++) {
      bfh[i] = *(const bf16x8*)(&BsH[cur][gsw2(cb + i * 16 + fr, g)]);
      bfl[i] = *(const bf16x8*)(&BsL[cur][gsw2(cb + i * 16 + fr, g)]);
    }
    #pragma unroll
    for (int mi = 0; mi < 2; mi++)
      #pragma unroll
      for (int ni = 0; ni < NFR; ni++) {
        acc[mi][ni] = MFMA_BF16(afh[mi], bfh[ni], acc[mi][ni]);
        acc[mi][ni] = MFMA_BF16(afl[mi], bfh[ni], acc[mi][ni]);
        acc[mi][ni] = MFMA_BF16(afh[mi], bfl[ni], acc[mi][ni]);
      }
    RBAR();
  }

  #pragma unroll
  for (int mi = 0; mi < 2; mi++) {
    #pragma unroll
    for (int ni = 0; ni < NFR; ni++) {
      int mrow = m0 + wr * 32 + mi * 16 + ((lane >> 4) << 2);
      int ocol = n0 + cb + ni * 16 + fr;
      if constexpr (EPI == 0) {          // fused QKV
        float bb = b0[ocol];
        if (ocol < 512) {
          bf16* Dh = (ocol < 256) ? o0 : o2;
          bf16* Dl = (ocol < 256) ? o1 : o3;
          int oo = ocol & 255;
          #pragma unroll
          for (int r = 0; r < 4; r++) {
            unsigned short hi, lo;
            tsplit(acc[mi][ni][r] + bb, hi, lo);
            Dh[(size_t)(mrow + r) * 256 + oo] = hi;
            Dl[(size_t)(mrow + r) * 256 + oo] = lo;
          }
        } else {
          int c = ocol - 512;
          int dbi = mrow >> 11, nn = mrow & 2047;
          u16x4 ph, pl;
          #pragma unroll
          for (int r = 0; r < 4; r++) {
            unsigned short hi, lo;
            tsplit(acc[mi][ni][r] + bb, hi, lo);
            ph[r] = hi; pl[r] = lo;
          }
          *(u16x4*)(&o4[((size_t)dbi * 256 + c) * 2048 + nn]) = ph;
          *(u16x4*)(&o5[((size_t)dbi * 256 + c) * 2048 + nn]) = pl;
        }
      } else if constexpr (EPI == 3) {   // BN+ReLU hi+lo
        float ge = b0[ocol], be = b1[ocol];
        #pragma unroll
        for (int r = 0; r < 4; r++) {
          unsigned short hi, lo;
          tsplit(fmaxf(ge * acc[mi][ni][r] + be, 0.f), hi, lo);
          o0[(size_t)(mrow + r) * 512 + ocol] = hi;
          o1[(size_t)(mrow + r) * 512 + ocol] = lo;
        }
      } else {                           // EPI 4: residual
        float bb = b0[ocol];
        #pragma unroll
        for (int r = 0; r < 4; r++) {
          size_t ix = (size_t)(mrow + r) * 256 + ocol;
          float d = of[ix] + acc[mi][ni][r] + bb;
          of[ix] = d;
          unsigned short hi, lo;
          tsplit(d, hi, lo);
          o0[(size_t)(mrow + r) * 512 + ocol] = hi;
          o1[(size_t)(mrow + r) * 512 + ocol] = lo;
        }
      }
    }
  }
}

// ---------------------------------------------------------------------------
// Flash attention (best measured): split-KV (2 halves), 8 waves x 16 q-rows,
// swapped QK^T (S[key][q=lane&15], per-lane softmax scalars), b64-packed
// P-store, 3-phase pipeline, defer-max. Emits unnormalized fp32 partial O
// + (m,l); attn_combine merges and writes into Hin/XMl cols 256:512.
// ---------------------------------------------------------------------------
DEVFN int swz(int row, int col) { return row * 64 + (col ^ ((row & 7) << 3)); }

__global__ __launch_bounds__(512, 4) void attn3s(
    const bf16* __restrict__ Qh, const bf16* __restrict__ Ql,
    const bf16* __restrict__ Kh, const bf16* __restrict__ Kl,
    const bf16* __restrict__ Vth, const bf16* __restrict__ Vtl,
    float* __restrict__ Pacc, float* __restrict__ Ml, int cross)
{
  __shared__ bf16 Ksh[64 * 64];
  __shared__ bf16 Ksl[64 * 64];
  __shared__ bf16 Vsh[64 * 64];
  __shared__ bf16 Vsl[64 * 64];
  __shared__ bf16 Psh[8][1024];
  __shared__ bf16 Psl[8][1024];
  int tid = threadIdx.x, lane = tid & 63, w = tid >> 6;
  int inst = blockIdx.y;
  int half = blockIdx.z;
  int db = inst >> 2, hd = inst & 3;
  int dsc = db >> 1, bi = db & 1;
  int sdb = (cross ? (1 - dsc) : dsc) * 2 + bi;
  size_t xq = (size_t)db * 2048;
  size_t xs = (size_t)sdb * 2048 + half * 1024;
  int n0 = blockIdx.x * 128;

  int fr = lane & 15, g = lane >> 4, kof = g << 3;

  // Q fragments hi/lo: direct global -> registers (row q = w*16 + fr)
  bf16x8 aqh[2], aql[2];
  #pragma unroll
  for (int kf = 0; kf < 2; kf++) {
    size_t gx = (xq + n0 + w * 16 + fr) * 256 + hd * 64 + kf * 32 + kof;
    aqh[kf] = *(const bf16x8*)(Qh + gx);
    aql[kf] = *(const bf16x8*)(Ql + gx);
  }

  f32x4 zero = {0.f, 0.f, 0.f, 0.f};
  f32x4 oacc[4];
  #pragma unroll
  for (int ni = 0; ni < 4; ni++) oacc[ni] = zero;
  float mrun = -3.0e38f, lrun = 0.f;   // per-lane: q = lane&15

  int lrow = lane >> 3;
  int g8 = ((lane & 7) ^ (lrow & 7)) << 3;
  int krow = w * 8 + lrow;
  const bf16* Ksrc_h = Kh + (xs + krow) * 256 + hd * 64 + g8;
  const bf16* Ksrc_l = Kl + (xs + krow) * 256 + hd * 64 + g8;
  const bf16* Vsrc_h = Vth + ((size_t)sdb * 256 + hd * 64 + krow) * 2048 + half * 1024 + g8;
  const bf16* Vsrc_l = Vtl + ((size_t)sdb * 256 + hd * 64 + krow) * 2048 + half * 1024 + g8;
  bf16* LKh = Ksh + w * 512;
  bf16* LKl = Ksl + w * 512;
  bf16* LVh = Vsh + w * 512;
  bf16* LVl = Vsl + w * 512;

  gll16(Ksrc_h, LKh);
  gll16(Ksrc_l, LKl);
  gll16(Vsrc_h, LVh);
  gll16(Vsrc_l, LVl);

  for (int t = 0; t < 16; t++) {
    VMW(4);            // K(t) landed; V(t) loads stay in flight
    RBAR(); SCHB();

    // ---- QK^T swapped: sacc[ni] = S[key = ni*16+4g+r][q = fr] ----
    f32x4 sacc[4];
    #pragma unroll
    for (int ni = 0; ni < 4; ni++) sacc[ni] = zero;
    #pragma unroll
    for (int kf = 0; kf < 2; kf++) {
      #pragma unroll
      for (int ni = 0; ni < 4; ni++) {
        bf16x8 bkh = *(const bf16x8*)(&Ksh[swz(ni * 16 + fr, kf * 32 + kof)]);
        bf16x8 bkl = *(const bf16x8*)(&Ksl[swz(ni * 16 + fr, kf * 32 + kof)]);
        sacc[ni] = MFMA_BF16(bkh, aqh[kf], sacc[ni]);
        sacc[ni] = MFMA_BF16(bkh, aql[kf], sacc[ni]);
        sacc[ni] = MFMA_BF16(bkl, aqh[kf], sacc[ni]);
      }
    }

    // ---- softmax, q local per lane: cheap defer-max check ----
    float tml = fmaxf(fmaxf(fmaxf(sacc[0][0], sacc[0][1]), fmaxf(sacc[0][2], sacc[0][3])),
               fmaxf(fmaxf(fmaxf(sacc[1][0], sacc[1][1]), fmaxf(sacc[1][2], sacc[1][3])),
               fmaxf(fmaxf(fmaxf(sacc[2][0], sacc[2][1]), fmaxf(sacc[2][2], sacc[2][3])),
                     fmaxf(fmaxf(sacc[3][0], sacc[3][1]), fmaxf(sacc[3][2], sacc[3][3])))));
    bool need = (tml > mrun + 8.0f);
    if (__ballot(need)) {
      float tm = fmaxf(tml, __shfl_xor(tml, 16));
      tm = fmaxf(tm, __shfl_xor(tm, 32));
      float mn = fmaxf(mrun, tm);
      float s = exp2f(mrun - mn);
      mrun = mn;
      lrun *= s;
      // oacc rows are q' = 4g + r; fetch s(q') from lane q' (group 0)
      #pragma unroll
      for (int r = 0; r < 4; r++) {
        float sr = __shfl(s, (g << 2) + r);
        #pragma unroll
        for (int ni = 0; ni < 4; ni++) oacc[ni][r] *= sr;
      }
    }
    float sum = 0.f;
    #pragma unroll
    for (int ni = 0; ni < 4; ni++)
      #pragma unroll
      for (int r = 0; r < 4; r++) {
        float pv = exp2f(sacc[ni][r] - mrun);
        sacc[ni][r] = pv;
        sum += pv;
      }
    sum += __shfl_xor(sum, 16);
    sum += __shfl_xor(sum, 32);
    lrun += sum;

    VMW(0);            // V(t) landed
    RBAR(); SCHB();

    if (t + 1 < 16) {  // K(t+1) flies under P-store + PV
      gll16(Ksrc_h + (size_t)(t + 1) * 16384, LKh);
      gll16(Ksrc_l + (size_t)(t + 1) * 16384, LKl);
    }

    // ---- P -> LDS, [q][key] layout, b64 packed (keys 4g..4g+3) ----
    bf16* Pwh = &Psh[w][0];
    bf16* Pwl = &Psl[w][0];
    #pragma unroll
    for (int ni = 0; ni < 4; ni++) {
      u16x4 ph, pl;
      #pragma unroll
      for (int r = 0; r < 4; r++) {
        unsigned short h0, l0;
        tsplit(sacc[ni][r], h0, l0);
        ph[r] = h0; pl[r] = l0;
      }
      int off = swz(fr, ni * 16 + (g << 2));   // 4-aligned col -> 8B aligned
      *(u16x4*)(&Pwh[off]) = ph;
      *(u16x4*)(&Pwl[off]) = pl;
    }

    // ---- PV (3-term); A-frag reads from [q][key] LDS ----
    #pragma unroll
    for (int kf = 0; kf < 2; kf++) {
      bf16x8 pah = *(const bf16x8*)(&Pwh[swz(fr, kf * 32 + kof)]);
      bf16x8 pal = *(const bf16x8*)(&Pwl[swz(fr, kf * 32 + kof)]);
      #pragma unroll
      for (int ni = 0; ni < 4; ni++) {
        bf16x8 bvh = *(const bf16x8*)(&Vsh[swz(ni * 16 + fr, kf * 32 + kof)]);
        bf16x8 bvl = *(const bf16x8*)(&Vsl[swz(ni * 16 + fr, kf * 32 + kof)]);
        oacc[ni] = MFMA_BF16(pah, bvh, oacc[ni]);
        oacc[ni] = MFMA_BF16(pal, bvh, oacc[ni]);
        oacc[ni] = MFMA_BF16(pah, bvl, oacc[ni]);
      }
    }

    RBAR();
    if (t + 1 < 16) {  // V(t+1) flies under next QK^T + softmax
      gll16(Vsrc_h + (t + 1) * 64, LVh);
      gll16(Vsrc_l + (t + 1) * 64, LVl);
    }
  }

  // store unnormalized partial O (fp32, rows q' = 4g+r) + per-row (m, l)
  float* Pb = Pacc + (size_t)half * 8192 * 256;
  #pragma unroll
  for (int r = 0; r < 4; r++) {
    int nrow = n0 + w * 16 + (g << 2) + r;
    size_t row = xq + nrow;
    #pragma unroll
    for (int ni = 0; ni < 4; ni++)
      Pb[row * 256 + hd * 64 + ni * 16 + fr] = oacc[ni][r];
  }
  if (lane < 16) {     // lane holds (mrun, lrun) for q = lane
    size_t row = xq + n0 + w * 16 + lane;
    float* mp = Ml + ((row * 4 + hd) << 2) + half * 2;
    mp[0] = mrun;
    mp[1] = lrun;
  }
}

// ---------------------------------------------------------------------------
// Combine the two KV halves; writes O directly into Hin/XMl cols 256:512.
// ---------------------------------------------------------------------------
__global__ __launch_bounds__(256) void attn_combine(
    const float* __restrict__ Pacc, const float* __restrict__ Ml,
    bf16* __restrict__ Hin, bf16* __restrict__ XMl)
{
  int tid = threadIdx.x, lane = tid & 63, w = tid >> 6;
  size_t row = (size_t)blockIdx.x * 4 + w;
  int hd = lane >> 4;
  int c0 = lane * 4;
  const float* mp = Ml + ((row * 4 + hd) << 2);
  float ma = mp[0], la = mp[1], mb = mp[2], lb = mp[3];
  float m = fmaxf(ma, mb);
  float wa = exp2f(ma - m), wb = exp2f(mb - m);
  float inv = 1.0f / (la * wa + lb * wb);
  wa *= inv; wb *= inv;
  f32x4 pa = *(const f32x4*)(Pacc + row * 256 + c0);
  f32x4 pb = *(const f32x4*)(Pacc + (size_t)8192 * 256 + row * 256 + c0);
  u16x4 vh, vl;
  #pragma unroll
  for (int r = 0; r < 4; r++) {
    unsigned short hi, lo;
    tsplit(pa[r] * wa + pb[r] * wb, hi, lo);
    vh[r] = hi; vl[r] = lo;
  }
  *(u16x4*)(Hin + row * 512 + 256 + c0) = vh;
  *(u16x4*)(XMl + row * 512 + 256 + c0) = vl;
}

// ---------------------------------------------------------------------------
extern "C" void kernel_launch(void* const* d_in, const int* in_sizes, int n_in,
                              void* d_out, int out_size, void* d_ws, size_t ws_size,
                              hipStream_t stream)
{
  (void)in_sizes; (void)n_in; (void)out_size; (void)ws_size;
  const float* desc0 = (const float*)d_in[0];
  const float* desc1 = (const float*)d_in[1];
  const float* Wq = (const float*)d_in[2];
  const float* bq = (const float*)d_in[3];
  const float* Wk = (const float*)d_in[4];
  const float* bk = (const float*)d_in[5];
  const float* Wv = (const float*)d_in[6];
  const float* bv = (const float*)d_in[7];
  const float* Wm = (const float*)d_in[8];
  const float* bm = (const float*)d_in[9];
  const float* W1 = (const float*)d_in[10];
  const float* b1 = (const float*)d_in[11];
  const float* gm = (const float*)d_in[12];
  const float* bt = (const float*)d_in[13];
  const float* W2 = (const float*)d_in[14];
  const float* b2 = (const float*)d_in[15];
  float* out = (float*)d_out;

  char* ws = (char*)d_ws;
  bf16*  Wbf  = (bf16*)(ws + 0);            //  31,457,280
  float* bias = (float*)(ws + 31457280);    //     110,592
  float* Dm   = (float*)(ws + 31567872);    //  16,777,216  fp32 master [xi,256]
  bf16*  Hin  = (bf16*)(ws + 48345088);     //  16,777,216  [xi,512] = xh | O_h
  bf16*  XMl  = (bf16*)(ws + 65122304);     //  16,777,216  [xi,512] = xl | O_l
  bf16*  Qh   = (bf16*)(ws + 81899520);     //   8,388,608
  bf16*  Ql   = (bf16*)(ws + 90288128);     //   8,388,608
  bf16*  Kh   = (bf16*)(ws + 98676736);     //   8,388,608
  bf16*  Kl   = (bf16*)(ws + 107065344);    //   8,388,608
  bf16*  Vth  = (bf16*)(ws + 115453952);    //   8,388,608  [db,256,2048]
  bf16*  Vtl  = (bf16*)(ws + 123842560);    //   8,388,608
  float* Pacc = (float*)(ws + 132231168);   //  16,777,216  [2][8192][256] fp32
  float* Ml   = (float*)(ws + 149008384);   //     524,288  [8192][4][4]
  // end: 149,532,672
  bf16*  Hbh  = Qh;                         // alias Qh+Ql (disjoint in time)
  bf16*  Hbl  = Kh;                         // alias Kh+Kl

  prep_weights<<<dim3(2313, 12), 256, 0, stream>>>(Wq, bq, Wk, bk, Wv, bv, Wm, bm,
                                                   W1, b1, gm, bt, W2, b2, Wbf, bias);
  prep_fold<<<dim3(64, 12), 256, 0, stream>>>(W1, Wm, bm, Wbf, bias);
  transpose_in<<<dim3(64, 8, 4), dim3(32, 8), 0, stream>>>(desc0, desc1, Dm, Hin, XMl);

  for (int l = 0; l < NL; l++) {
    const bf16* wl = Wbf + (size_t)l * 1310720;
    const float* bl = bias + l * 2304;
    int cross = l & 1;
    // fused QKV (Q pre-scaled by log2e/8): 768 blocks = 3/CU
    gemm3<0, 128><<<dim3(128, 6), 256, 0, stream>>>(Hin, 512, XMl, 512,
        wl, wl + 196608, 256, bl, nullptr,
        Qh, Ql, Kh, Kl, Vth, Vtl, nullptr);
    // split-KV attention + combine (combine writes O into Hin/XMl msg-half)
    attn3s<<<dim3(16, 16, 2), 512, 0, stream>>>(Qh, Ql, Kh, Kl, Vth, Vtl,
                                                Pacc, Ml, cross);
    attn_combine<<<2048, 256, 0, stream>>>(Pacc, Ml, Hin, XMl);
    // MLP1 (merge folded in): 512 blocks = 2/CU
    gemm3<3, 128><<<dim3(128, 4), 256, 0, stream>>>(Hin, 512, XMl, 512,
        wl + 524288, wl + 786432, 512, bl + 1024, bl + 1536,
        Hbh, Hbl, nullptr, nullptr, nullptr, nullptr, nullptr);
    // MLP2 + residual: 512 blocks = 2/CU
    gemm3<4, 64><<<dim3(128, 4), 256, 0, stream>>>(Hbh, 512, Hbl, 512,
        wl + 1048576, wl + 1179648, 512, bl + 2048, nullptr,
        Hin, XMl, nullptr, nullptr, nullptr, nullptr, Dm);
  }
  transpose_out<<<dim3(64, 8, 4), dim3(32, 8), 0, stream>>>(Dm, out);
}